// Round 1
// baseline (658.169 us; speedup 1.0000x reference)
//
#include <hip/hip_runtime.h>
#include <hip/hip_bf16.h>

typedef __hip_bfloat16 bf16;
typedef __attribute__((ext_vector_type(8))) short bf16x8;
typedef __attribute__((ext_vector_type(4))) float f32x4;

static constexpr int B = 2, S = 2048, D = 2048, H = 32, HK = 8, HD = 64;
static constexpr int M = B * S;          // 4096 tokens
static constexpr int NKV = HK * HD;      // 512
static constexpr float SM_SCALE = 0.125f; // 1/sqrt(64)

// ---------------- cast fp32 -> bf16 (vectorized x4) ----------------
struct alignas(8) bf4 { bf16 v[4]; };
__global__ __launch_bounds__(256) void cast_bf16_kernel(const float* __restrict__ in,
                                                        bf16* __restrict__ out, int n4) {
  int i = blockIdx.x * 256 + threadIdx.x;
  int stride = gridDim.x * 256;
  for (; i < n4; i += stride) {
    float4 f = reinterpret_cast<const float4*>(in)[i];
    bf4 o;
    o.v[0] = __float2bfloat16(f.x);
    o.v[1] = __float2bfloat16(f.y);
    o.v[2] = __float2bfloat16(f.z);
    o.v[3] = __float2bfloat16(f.w);
    reinterpret_cast<bf4*>(out)[i] = o;
  }
}

// ---------------- GEMM: C[M][N] = A[M][K] @ Bt[N][K]^T, bf16 in, f32 acc ----
template <bool OUT_F32>
__global__ __launch_bounds__(256) void gemm_bt_kernel(const bf16* __restrict__ A,
                                                      const bf16* __restrict__ Bt,
                                                      void* __restrict__ C,
                                                      int Ndim, int Kdim) {
  // 128x128 tile, BK=64, 4 waves in 2x2; XOR-swizzled LDS (16B granules)
  __shared__ __align__(16) bf16 As[128][64];
  __shared__ __align__(16) bf16 Bs[128][64];
  const int tid = threadIdx.x;
  const int lane = tid & 63;
  const int w = tid >> 6;
  const int wm = w >> 1, wn = w & 1;
  const int r16 = lane & 15, g = lane >> 4;
  const int bm = blockIdx.y, bn = blockIdx.x;
  f32x4 acc[4][4] = {};

  const int nk = Kdim >> 6;
  for (int kt = 0; kt < nk; ++kt) {
    __syncthreads();
#pragma unroll
    for (int i = 0; i < 4; ++i) {
      int u = tid + i * 256;           // 0..1023 : 128 rows x 8 16B-chunks
      int r = u >> 3, c8 = u & 7;
      int sw = (c8 ^ (r & 7)) * 8;
      *reinterpret_cast<bf16x8*>(&As[r][sw]) =
          *reinterpret_cast<const bf16x8*>(&A[(size_t)(bm * 128 + r) * Kdim + kt * 64 + c8 * 8]);
      *reinterpret_cast<bf16x8*>(&Bs[r][sw]) =
          *reinterpret_cast<const bf16x8*>(&Bt[(size_t)(bn * 128 + r) * Kdim + kt * 64 + c8 * 8]);
    }
    __syncthreads();
#pragma unroll
    for (int kc = 0; kc < 2; ++kc) {
      bf16x8 af[4], bfr[4];
      const int kq = kc * 4 + g;       // logical 16B-chunk index within BK=64
#pragma unroll
      for (int m = 0; m < 4; ++m) {
        int ra = wm * 64 + m * 16 + r16;
        af[m] = *reinterpret_cast<const bf16x8*>(&As[ra][(kq ^ (ra & 7)) * 8]);
        int rb = wn * 64 + m * 16 + r16;
        bfr[m] = *reinterpret_cast<const bf16x8*>(&Bs[rb][(kq ^ (rb & 7)) * 8]);
      }
#pragma unroll
      for (int m = 0; m < 4; ++m)
#pragma unroll
        for (int n = 0; n < 4; ++n)
          acc[m][n] = __builtin_amdgcn_mfma_f32_16x16x32_bf16(af[m], bfr[n], acc[m][n], 0, 0, 0);
    }
  }
  // epilogue: D layout row=(lane>>4)*4+j, col=lane&15
  const int row0 = bm * 128 + wm * 64 + g * 4;
  const int col0 = bn * 128 + wn * 64 + r16;
#pragma unroll
  for (int m = 0; m < 4; ++m)
#pragma unroll
    for (int n = 0; n < 4; ++n)
#pragma unroll
      for (int j = 0; j < 4; ++j) {
        size_t idx = (size_t)(row0 + m * 16 + j) * Ndim + col0 + n * 16;
        if (OUT_F32)
          reinterpret_cast<float*>(C)[idx] = acc[m][n][j];
        else
          reinterpret_cast<bf16*>(C)[idx] = __float2bfloat16(acc[m][n][j]);
      }
}

// ---------------- RoPE in-place on [b][s][nheads][64] ----------------
__global__ __launch_bounds__(256) void rope_kernel(bf16* __restrict__ t,
                                                   const float* __restrict__ cosb,
                                                   const float* __restrict__ sinb,
                                                   int nheads) {
  int idx = blockIdx.x * 256 + threadIdx.x;  // B*S*nheads*32 threads exactly
  int i = idx & 31;
  int rest = idx >> 5;
  int hh = rest % nheads;
  int s = (rest / nheads) % S;
  int b = rest / (nheads * S);
  size_t base = (((size_t)b * S + s) * nheads + hh) * HD;
  float x0 = __bfloat162float(t[base + i]);
  float x1 = __bfloat162float(t[base + i + 32]);
  float c = cosb[s * HD + i];
  float sn = sinb[s * HD + i];
  t[base + i] = __float2bfloat16(x0 * c - x1 * sn);
  t[base + i + 32] = __float2bfloat16(x1 * c + x0 * sn);
}

// ---------------- V transpose: [b][s][hk][64] -> [b][hk][64][s] ----------------
__global__ __launch_bounds__(256) void transpose_v_kernel(const bf16* __restrict__ v,
                                                          bf16* __restrict__ vt) {
  __shared__ bf16 tile[64][65];
  const int st = blockIdx.x;      // s-tile of 64
  const int bk = blockIdx.y;      // b*HK + hk
  const int b = bk >> 3, hk = bk & 7;
  const int tid = threadIdx.x;
#pragma unroll
  for (int i = 0; i < 16; ++i) {
    int idx = tid + i * 256;
    int rs = idx >> 6, c = idx & 63;
    tile[rs][c] = v[(((size_t)b * S + st * 64 + rs) * HK + hk) * HD + c];
  }
  __syncthreads();
#pragma unroll
  for (int i = 0; i < 16; ++i) {
    int idx = tid + i * 256;
    int rh = idx >> 6, cs = idx & 63;
    vt[(((size_t)b * HK + hk) * HD + rh) * S + st * 64 + cs] = tile[cs][rh];
  }
}

// ---------------- causal flash attention (GQA) ----------------
// q: [b][s][H][64] (roped), k: [b][s][HK][64] (roped), vt: [b][hk][64][S]
// ao: [b][s][H*64] bf16
__global__ __launch_bounds__(256) void attn_kernel(const bf16* __restrict__ q,
                                                   const bf16* __restrict__ k,
                                                   const bf16* __restrict__ vt,
                                                   bf16* __restrict__ ao) {
  __shared__ __align__(16) bf16 Pb[4][16][32];  // per-wave P round-trip
  const int qb = blockIdx.x;       // q tile of 64 rows
  const int bh = blockIdx.y;       // b*H + h
  const int b = bh >> 5;
  const int h = bh & 31;
  const int hk = h >> 2;           // REP=4
  const int tid = threadIdx.x;
  const int lane = tid & 63;
  const int w = tid >> 6;
  const int r = lane & 15, g = lane >> 4;
  const int sq_base = qb * 64 + w * 16;

  // Q fragments (A-operand): row = lane&15, k = (lane>>4)*8+j
  bf16x8 qf0, qf1;
  {
    const bf16* qp = &q[(((size_t)b * S + sq_base + r) * H + h) * HD + g * 8];
    qf0 = *reinterpret_cast<const bf16x8*>(qp);
    qf1 = *reinterpret_cast<const bf16x8*>(qp + 32);
  }
  float mr[4], lr[4];
  f32x4 o[4] = {};
#pragma unroll
  for (int j = 0; j < 4; ++j) { mr[j] = -1e30f; lr[j] = 0.f; }

  const int kend = sq_base + 16;   // causal bound for this wave's rows
  for (int kv0 = 0; kv0 < kend; kv0 += 32) {
    // scores: two 16-col chunks, K-dim = HD = 64 (2 MFMAs each)
    f32x4 sc[2];
#pragma unroll
    for (int cc = 0; cc < 2; ++cc) {
      const bf16* kp = &k[(((size_t)b * S + kv0 + cc * 16 + r) * HK + hk) * HD + g * 8];
      bf16x8 kf0 = *reinterpret_cast<const bf16x8*>(kp);
      bf16x8 kf1 = *reinterpret_cast<const bf16x8*>(kp + 32);
      f32x4 z = {};
      z = __builtin_amdgcn_mfma_f32_16x16x32_bf16(qf0, kf0, z, 0, 0, 0);
      z = __builtin_amdgcn_mfma_f32_16x16x32_bf16(qf1, kf1, z, 0, 0, 0);
      sc[cc] = z;
    }
    // online softmax per row (rows g*4+j, cols across 16 lanes of the group)
    float scl[4], p0[4], p1[4];
#pragma unroll
    for (int j = 0; j < 4; ++j) {
      const int sq = sq_base + g * 4 + j;
      float v0 = (kv0 + r <= sq) ? sc[0][j] * SM_SCALE : -1e30f;
      float v1 = (kv0 + 16 + r <= sq) ? sc[1][j] * SM_SCALE : -1e30f;
      float t = fmaxf(v0, v1);
      t = fmaxf(t, __shfl_xor(t, 1, 16));
      t = fmaxf(t, __shfl_xor(t, 2, 16));
      t = fmaxf(t, __shfl_xor(t, 4, 16));
      t = fmaxf(t, __shfl_xor(t, 8, 16));
      float mn = fmaxf(mr[j], t);
      scl[j] = __expf(mr[j] - mn);
      mr[j] = mn;
      p0[j] = __expf(v0 - mn);
      p1[j] = __expf(v1 - mn);
      float ps = p0[j] + p1[j];
      ps += __shfl_xor(ps, 1, 16);
      ps += __shfl_xor(ps, 2, 16);
      ps += __shfl_xor(ps, 4, 16);
      ps += __shfl_xor(ps, 8, 16);
      lr[j] = lr[j] * scl[j] + ps;
    }
    // P (D-layout) -> LDS -> A-layout fragment
#pragma unroll
    for (int j = 0; j < 4; ++j) {
      Pb[w][g * 4 + j][r] = __float2bfloat16(p0[j]);
      Pb[w][g * 4 + j][16 + r] = __float2bfloat16(p1[j]);
    }
    asm volatile("s_waitcnt lgkmcnt(0)" ::: "memory");
    bf16x8 paf = *reinterpret_cast<const bf16x8*>(&Pb[w][r][g * 8]);
    // rescale O
#pragma unroll
    for (int n = 0; n < 4; ++n) {
      o[n][0] *= scl[0]; o[n][1] *= scl[1]; o[n][2] *= scl[2]; o[n][3] *= scl[3];
    }
    // PV: B-operand from Vt (contiguous along kv)
#pragma unroll
    for (int n = 0; n < 4; ++n) {
      const bf16* vp = &vt[(((size_t)b * HK + hk) * HD + n * 16 + r) * S + kv0 + g * 8];
      bf16x8 vf = *reinterpret_cast<const bf16x8*>(vp);
      o[n] = __builtin_amdgcn_mfma_f32_16x16x32_bf16(paf, vf, o[n], 0, 0, 0);
    }
  }
  // epilogue: normalize and store to [b][s][h*64+hd]
#pragma unroll
  for (int n = 0; n < 4; ++n)
#pragma unroll
    for (int j = 0; j < 4; ++j) {
      float val = o[n][j] / lr[j];
      size_t idx = ((size_t)b * S + sq_base + g * 4 + j) * D + h * HD + n * 16 + r;
      ao[idx] = __float2bfloat16(val);
    }
}

extern "C" void kernel_launch(void* const* d_in, const int* in_sizes, int n_in,
                              void* d_out, int out_size, void* d_ws, size_t ws_size,
                              hipStream_t stream) {
  (void)in_sizes; (void)n_in; (void)out_size; (void)ws_size;
  const float* x    = (const float*)d_in[0];
  const float* cosb = (const float*)d_in[1];
  const float* sinb = (const float*)d_in[2];
  // d_in[3] = attn_mask (causal, unused)
  const float* wq   = (const float*)d_in[4];
  const float* wk   = (const float*)d_in[5];
  const float* wv   = (const float*)d_in[6];
  const float* wo   = (const float*)d_in[7];

  char* ws = (char*)d_ws;
  size_t off = 0;
  auto alloc = [&](size_t elems) {
    bf16* p = (bf16*)(ws + off);
    off = (off + elems * sizeof(bf16) + 255) & ~(size_t)255;
    return p;
  };
  bf16* xb  = alloc((size_t)M * D);
  bf16* wqb = alloc((size_t)D * D);
  bf16* wkb = alloc((size_t)NKV * D);
  bf16* wvb = alloc((size_t)NKV * D);
  bf16* wob = alloc((size_t)D * D);
  bf16* qb  = alloc((size_t)M * D);
  bf16* kb  = alloc((size_t)M * NKV);
  bf16* vb  = alloc((size_t)M * NKV);
  bf16* vtb = alloc((size_t)M * NKV);
  bf16* aob = alloc((size_t)M * D);

  auto cast = [&](const float* src, bf16* dst, size_t n) {
    int n4 = (int)(n / 4);
    int blocks = (n4 + 255) / 256;
    if (blocks > 2048) blocks = 2048;
    cast_bf16_kernel<<<dim3(blocks), dim3(256), 0, stream>>>(src, dst, n4);
  };
  cast(x, xb, (size_t)M * D);
  cast(wq, wqb, (size_t)D * D);
  cast(wk, wkb, (size_t)NKV * D);
  cast(wv, wvb, (size_t)NKV * D);
  cast(wo, wob, (size_t)D * D);

  // projections
  gemm_bt_kernel<false><<<dim3(D / 128, M / 128), 256, 0, stream>>>(xb, wqb, qb, D, D);
  gemm_bt_kernel<false><<<dim3(NKV / 128, M / 128), 256, 0, stream>>>(xb, wkb, kb, NKV, D);
  gemm_bt_kernel<false><<<dim3(NKV / 128, M / 128), 256, 0, stream>>>(xb, wvb, vb, NKV, D);

  // rope q, k
  rope_kernel<<<dim3(B * S * H * 32 / 256), 256, 0, stream>>>(qb, cosb, sinb, H);
  rope_kernel<<<dim3(B * S * HK * 32 / 256), 256, 0, stream>>>(kb, cosb, sinb, HK);

  // v transpose for PV B-operand
  transpose_v_kernel<<<dim3(S / 64, B * HK), 256, 0, stream>>>(vb, vtb);

  // attention
  attn_kernel<<<dim3(S / 64, B * H), 256, 0, stream>>>(qb, kb, vtb, aob);

  // output projection (fp32 out)
  gemm_bt_kernel<true><<<dim3(D / 128, M / 128), 256, 0, stream>>>(aob, wob, d_out, D, D);
}

// Round 2
// 373.509 us; speedup vs baseline: 1.7621x; 1.7621x over previous
//
#include <hip/hip_runtime.h>
#include <hip/hip_bf16.h>

typedef __hip_bfloat16 bf16;
typedef __attribute__((ext_vector_type(8))) short bf16x8;
typedef __attribute__((ext_vector_type(4))) short short4v;
typedef __attribute__((ext_vector_type(4))) float f32x4;

static constexpr int B = 2, S = 2048, D = 2048, H = 32, HK = 8, HD = 64;
static constexpr int M = B * S;           // 4096 tokens
static constexpr int NKV = HK * HD;       // 512
static constexpr int NKV2 = 2 * NKV;      // 1024 (K|V fused)
static constexpr float SM_SCALE = 0.125f; // 1/sqrt(64)

__device__ __forceinline__ short bfbits(float x) {
  bf16 h = __float2bfloat16(x);
  return *reinterpret_cast<short*>(&h);
}

__device__ __forceinline__ void gl_lds16(const bf16* gp, bf16* lp) {
  __builtin_amdgcn_global_load_lds(
      (const __attribute__((address_space(1))) unsigned int*)(const void*)gp,
      (__attribute__((address_space(3))) unsigned int*)(void*)lp, 16, 0, 0);
}

// ---------------- cast fp32 -> bf16 (vectorized x4) ----------------
struct alignas(8) bf4 { bf16 v[4]; };
__global__ __launch_bounds__(256) void cast_bf16_kernel(const float* __restrict__ in,
                                                        bf16* __restrict__ out, int n4) {
  int i = blockIdx.x * 256 + threadIdx.x;
  int stride = gridDim.x * 256;
  for (; i < n4; i += stride) {
    float4 f = reinterpret_cast<const float4*>(in)[i];
    bf4 o;
    o.v[0] = __float2bfloat16(f.x);
    o.v[1] = __float2bfloat16(f.y);
    o.v[2] = __float2bfloat16(f.z);
    o.v[3] = __float2bfloat16(f.w);
    reinterpret_cast<bf4*>(out)[i] = o;
  }
}

// ---------------- GEMM: C[M][N] = A[M][K] @ Bt[N][K]^T, bf16 in, f32 acc ----
// 128x128 tile, BK=64; global_load_lds(16B) staging: linear LDS dest +
// pre-swizzled global source (involution XOR on 16B chunk index).
template <bool OUT_F32>
__global__ __launch_bounds__(256) void gemm_bt_kernel(const bf16* __restrict__ A,
                                                      const bf16* __restrict__ Bt,
                                                      void* __restrict__ C,
                                                      int Ndim, int Kdim) {
  __shared__ __align__(16) bf16 As[128][64];
  __shared__ __align__(16) bf16 Bs[128][64];
  const int tid = threadIdx.x;
  const int lane = tid & 63;
  const int w = tid >> 6;
  const int wm = w >> 1, wn = w & 1;
  const int r16 = lane & 15, g = lane >> 4;
  const int bm = blockIdx.y, bn = blockIdx.x;
  f32x4 acc[4][4] = {};

  const int nk = Kdim >> 6;
  for (int kt = 0; kt < nk; ++kt) {
    __syncthreads();
#pragma unroll
    for (int i = 0; i < 4; ++i) {
      int u = tid + i * 256;           // 0..1023 : 128 rows x 8 16B-chunks
      int rr = u >> 3, c8 = u & 7;
      int c8s = c8 ^ (rr & 7);         // pre-swizzled source chunk
      gl_lds16(&A[(size_t)(bm * 128 + rr) * Kdim + kt * 64 + c8s * 8], &As[0][0] + (size_t)u * 8);
      gl_lds16(&Bt[(size_t)(bn * 128 + rr) * Kdim + kt * 64 + c8s * 8], &Bs[0][0] + (size_t)u * 8);
    }
    __syncthreads();
#pragma unroll
    for (int kc = 0; kc < 2; ++kc) {
      bf16x8 af[4], bfr[4];
      const int kq = kc * 4 + g;       // logical 16B-chunk index within BK=64
#pragma unroll
      for (int m = 0; m < 4; ++m) {
        int ra = wm * 64 + m * 16 + r16;
        af[m] = *reinterpret_cast<const bf16x8*>(&As[ra][(kq ^ (ra & 7)) * 8]);
        int rb = wn * 64 + m * 16 + r16;
        bfr[m] = *reinterpret_cast<const bf16x8*>(&Bs[rb][(kq ^ (rb & 7)) * 8]);
      }
#pragma unroll
      for (int m = 0; m < 4; ++m)
#pragma unroll
        for (int n = 0; n < 4; ++n)
          acc[m][n] = __builtin_amdgcn_mfma_f32_16x16x32_bf16(af[m], bfr[n], acc[m][n], 0, 0, 0);
    }
  }
  const int row0 = bm * 128 + wm * 64 + g * 4;
  const int col0 = bn * 128 + wn * 64 + r16;
#pragma unroll
  for (int m = 0; m < 4; ++m)
#pragma unroll
    for (int n = 0; n < 4; ++n)
#pragma unroll
      for (int j = 0; j < 4; ++j) {
        size_t idx = (size_t)(row0 + m * 16 + j) * Ndim + col0 + n * 16;
        if (OUT_F32)
          reinterpret_cast<float*>(C)[idx] = acc[m][n][j];
        else
          reinterpret_cast<bf16*>(C)[idx] = __float2bfloat16(acc[m][n][j]);
      }
}

// ---------------- RoPE in-place, row stride parametrized ----------------
__global__ __launch_bounds__(256) void rope_kernel(bf16* __restrict__ t,
                                                   const float* __restrict__ cosb,
                                                   const float* __restrict__ sinb,
                                                   int nheads, int rowstride) {
  int idx = blockIdx.x * 256 + threadIdx.x;  // B*S*nheads*32 threads exactly
  int i = idx & 31;
  int rest = idx >> 5;
  int hh = rest % nheads;
  int s = (rest / nheads) % S;
  int b = rest / (nheads * S);
  size_t base = ((size_t)b * S + s) * rowstride + hh * HD;
  float x0 = __bfloat162float(t[base + i]);
  float x1 = __bfloat162float(t[base + i + 32]);
  float c = cosb[s * HD + i];
  float sn = sinb[s * HD + i];
  t[base + i] = __float2bfloat16(x0 * c - x1 * sn);
  t[base + i + 32] = __float2bfloat16(x1 * c + x0 * sn);
}

// ---------------- V transpose: kv[b][s][1024] cols 512+ -> vt[b][hk][64][S] ----
__global__ __launch_bounds__(256) void transpose_v_kernel(const bf16* __restrict__ kv,
                                                          bf16* __restrict__ vt) {
  __shared__ bf16 tile[64][65];
  const int st = blockIdx.x;      // s-tile of 64
  const int bk = blockIdx.y;      // b*HK + hk
  const int b = bk >> 3, hk = bk & 7;
  const int tid = threadIdx.x;
#pragma unroll
  for (int i = 0; i < 16; ++i) {
    int idx = tid + i * 256;
    int rs = idx >> 6, c = idx & 63;
    tile[rs][c] = kv[((size_t)b * S + st * 64 + rs) * NKV2 + NKV + hk * HD + c];
  }
  __syncthreads();
#pragma unroll
  for (int i = 0; i < 16; ++i) {
    int idx = tid + i * 256;
    int rh = idx >> 6, cs = idx & 63;
    vt[(((size_t)b * HK + hk) * HD + rh) * S + st * 64 + cs] = tile[cs][rh];
  }
}

// ---------------- causal flash attention (GQA), swapped-operand, 1 wave/block --
// q: [b][s][H][64] roped; kv: [b][s][1024] (K cols 0..511 roped); vt: [b][hk][64][S]
// ao: [b][s][H*64] bf16.  Wave u does q-tiles u*32 and 2016-u*32 (perfect balance).
__global__ __launch_bounds__(64) void attn_kernel(const bf16* __restrict__ q,
                                                  const bf16* __restrict__ kv,
                                                  const bf16* __restrict__ vt,
                                                  bf16* __restrict__ ao) {
  const int u = blockIdx.x;        // 0..31
  const int bh = blockIdx.y;       // b*H + h
  const int b = bh >> 5;
  const int h = bh & 31;
  const int hk = h >> 2;
  const int lane = threadIdx.x;
  const int r = lane & 15, g = lane >> 4;

  for (int pass = 0; pass < 2; ++pass) {
    const int qb = pass ? (2016 - u * 32) : (u * 32);
    // Q fragments (B-operand of S^T): col=q=lane&15, k=hd=g*8+j (+32*hc)
    bf16x8 qfr[2][2];
#pragma unroll
    for (int qq = 0; qq < 2; ++qq)
#pragma unroll
      for (int hc = 0; hc < 2; ++hc)
        qfr[qq][hc] = *reinterpret_cast<const bf16x8*>(
            &q[(((size_t)b * S + qb + qq * 16 + r) * H + h) * HD + hc * 32 + g * 8]);

    float mreg[2] = {-1e30f, -1e30f}, lreg[2] = {0.f, 0.f};
    f32x4 o[4][2] = {};              // [hd frag][q frag]
    const int kv_end = qb + 32;
    for (int kv0 = 0; kv0 < kv_end; kv0 += 64) {
      const bool lastc = (kv0 + 64 >= kv_end);   // only chunk needing the causal mask
      // S^T[kv][q]: A=K (row=kv, k=hd)
      f32x4 sc[4][2] = {};
#pragma unroll
      for (int f = 0; f < 4; ++f)
#pragma unroll
        for (int hc = 0; hc < 2; ++hc) {
          bf16x8 kf = *reinterpret_cast<const bf16x8*>(
              &kv[((size_t)b * S + kv0 + f * 16 + r) * NKV2 + hk * HD + hc * 32 + g * 8]);
          sc[f][0] = __builtin_amdgcn_mfma_f32_16x16x32_bf16(kf, qfr[0][hc], sc[f][0], 0, 0, 0);
          sc[f][1] = __builtin_amdgcn_mfma_f32_16x16x32_bf16(kf, qfr[1][hc], sc[f][1], 0, 0, 0);
        }
      // in-register online softmax per q-column (lane-local kv axis)
      bf16x8 pb[4][2];
#pragma unroll
      for (int qq = 0; qq < 2; ++qq) {
        const int qi = qb + qq * 16 + r;
        float vals[4][4];
#pragma unroll
        for (int f = 0; f < 4; ++f)
#pragma unroll
          for (int j = 0; j < 4; ++j)
            vals[f][j] = sc[f][qq][j] * SM_SCALE;
        if (lastc) {
#pragma unroll
          for (int f = 0; f < 4; ++f)
#pragma unroll
            for (int j = 0; j < 4; ++j)
              if (kv0 + f * 16 + g * 4 + j > qi) vals[f][j] = -1e30f;
        }
        float mx = -1e30f;
#pragma unroll
        for (int f = 0; f < 4; ++f)
#pragma unroll
          for (int j = 0; j < 4; ++j) mx = fmaxf(mx, vals[f][j]);
        mx = fmaxf(mx, __shfl_xor(mx, 16));
        mx = fmaxf(mx, __shfl_xor(mx, 32));
        float mn = fmaxf(mreg[qq], mx);
        float scl = __expf(mreg[qq] - mn);
        mreg[qq] = mn;
        float ls = 0.f;
#pragma unroll
        for (int f = 0; f < 4; ++f) {
          bf16x8 pp = {};
#pragma unroll
          for (int j = 0; j < 4; ++j) {
            float p = __expf(vals[f][j] - mn);
            ls += p;
            pp[j] = bfbits(p);
          }
          pb[f][qq] = pp;              // B-frag k=g*4+j (j<4), upper half zero
        }
        ls += __shfl_xor(ls, 16);
        ls += __shfl_xor(ls, 32);
        lreg[qq] = lreg[qq] * scl + ls;
#pragma unroll
        for (int d = 0; d < 4; ++d) {
          o[d][qq][0] *= scl; o[d][qq][1] *= scl;
          o[d][qq][2] *= scl; o[d][qq][3] *= scl;
        }
      }
      // O^T += V^T @ P^T : A=vt (row=hd, k=kv), zero-padded k=4..7 both sides
#pragma unroll
      for (int d = 0; d < 4; ++d)
#pragma unroll
        for (int f = 0; f < 4; ++f) {
          short4v v4 = *reinterpret_cast<const short4v*>(
              &vt[(((size_t)b * HK + hk) * HD + d * 16 + r) * S + kv0 + f * 16 + g * 4]);
          bf16x8 v8 = {};
          v8[0] = v4[0]; v8[1] = v4[1]; v8[2] = v4[2]; v8[3] = v4[3];
          o[d][0] = __builtin_amdgcn_mfma_f32_16x16x32_bf16(v8, pb[f][0], o[d][0], 0, 0, 0);
          o[d][1] = __builtin_amdgcn_mfma_f32_16x16x32_bf16(v8, pb[f][1], o[d][1], 0, 0, 0);
        }
    }
    // epilogue: O^T D-layout: col=q=lane&15, row=hd=g*4+j (j contiguous in hd)
#pragma unroll
    for (int qq = 0; qq < 2; ++qq) {
      float inv = 1.0f / lreg[qq];
#pragma unroll
      for (int d = 0; d < 4; ++d) {
        short4v ov;
        ov[0] = bfbits(o[d][qq][0] * inv);
        ov[1] = bfbits(o[d][qq][1] * inv);
        ov[2] = bfbits(o[d][qq][2] * inv);
        ov[3] = bfbits(o[d][qq][3] * inv);
        *reinterpret_cast<short4v*>(
            &ao[(((size_t)b * S + qb + qq * 16 + r) * H + h) * HD + d * 16 + g * 4]) = ov;
      }
    }
  }
}

extern "C" void kernel_launch(void* const* d_in, const int* in_sizes, int n_in,
                              void* d_out, int out_size, void* d_ws, size_t ws_size,
                              hipStream_t stream) {
  (void)in_sizes; (void)n_in; (void)out_size; (void)ws_size;
  const float* x    = (const float*)d_in[0];
  const float* cosb = (const float*)d_in[1];
  const float* sinb = (const float*)d_in[2];
  // d_in[3] = attn_mask (causal, unused)
  const float* wq   = (const float*)d_in[4];
  const float* wk   = (const float*)d_in[5];
  const float* wv   = (const float*)d_in[6];
  const float* wo   = (const float*)d_in[7];

  char* ws = (char*)d_ws;
  size_t off = 0;
  auto alloc = [&](size_t elems) {
    bf16* p = (bf16*)(ws + off);
    off = (off + elems * sizeof(bf16) + 255) & ~(size_t)255;
    return p;
  };
  bf16* xb   = alloc((size_t)M * D);
  bf16* wqb  = alloc((size_t)D * D);
  bf16* wkvb = alloc((size_t)NKV2 * D);   // K weights then V weights, contiguous
  bf16* wob  = alloc((size_t)D * D);
  bf16* qb   = alloc((size_t)M * D);
  bf16* kvb  = alloc((size_t)M * NKV2);   // fused K|V activations
  bf16* vtb  = alloc((size_t)B * HK * HD * S);
  bf16* aob  = alloc((size_t)M * D);

  auto cast = [&](const float* src, bf16* dst, size_t n) {
    int n4 = (int)(n / 4);
    int blocks = (n4 + 255) / 256;
    if (blocks > 2048) blocks = 2048;
    cast_bf16_kernel<<<dim3(blocks), dim3(256), 0, stream>>>(src, dst, n4);
  };
  cast(x, xb, (size_t)M * D);
  cast(wq, wqb, (size_t)D * D);
  cast(wk, wkvb, (size_t)NKV * D);
  cast(wv, wkvb + (size_t)NKV * D, (size_t)NKV * D);
  cast(wo, wob, (size_t)D * D);

  // projections (Q; fused K|V)
  gemm_bt_kernel<false><<<dim3(D / 128, M / 128), 256, 0, stream>>>(xb, wqb, qb, D, D);
  gemm_bt_kernel<false><<<dim3(NKV2 / 128, M / 128), 256, 0, stream>>>(xb, wkvb, kvb, NKV2, D);

  // rope q (stride D) and k-part of kv (stride 1024, first 8 head-slots)
  rope_kernel<<<dim3(B * S * H * 32 / 256), 256, 0, stream>>>(qb, cosb, sinb, H, D);
  rope_kernel<<<dim3(B * S * HK * 32 / 256), 256, 0, stream>>>(kvb, cosb, sinb, HK, NKV2);

  // v transpose for PV A-operand
  transpose_v_kernel<<<dim3(S / 64, B * HK), 256, 0, stream>>>(kvb, vtb);

  // attention: 1 wave per block, balanced front/back q-tile pairing
  attn_kernel<<<dim3(32, B * H), 64, 0, stream>>>(qb, kvb, vtb, aob);

  // output projection (fp32 out)
  gemm_bt_kernel<true><<<dim3(D / 128, M / 128), 256, 0, stream>>>(aob, wob, d_out, D, D);
}